// Round 1
// baseline (294.068 us; speedup 1.0000x reference)
//
#include <hip/hip_runtime.h>
#include <hip/hip_bf16.h>
#include <math.h>

#define RESX 64
#define NVOX (RESX * RESX * RESX)   // 262144
#define FDIM 32
#define NMOD 3
#define HID 64
#define NCLS 4
#define NFREQ 6
#define INDIM 135                   // 96 + 3 + 36
#define TPB 64                      // points per block
#define XSTR 65                     // LDS row stride (floats); odd -> conflict-free

// ---------------------------------------------------------------------------
// Kernel 1: transpose grids [m][c][64^3] f32  ->  [m][voxel][c] bf16 in d_ws
// ---------------------------------------------------------------------------
__global__ void transpose_grids_kernel(const float* __restrict__ g,
                                       __hip_bfloat16* __restrict__ gt) {
    __shared__ float tile[FDIM][65];
    const int b  = blockIdx.x;          // NMOD * 4096 blocks
    const int m  = b >> 12;
    const int v0 = (b & 4095) << 6;     // 64 voxels per block
    const int t  = threadIdx.x;
#pragma unroll
    for (int pass = 0; pass < 8; ++pass) {
        const int c = pass * 4 + (t >> 6);
        const int v = t & 63;
        tile[c][v] = g[(size_t)(m * FDIM + c) * NVOX + v0 + v];
    }
    __syncthreads();
#pragma unroll
    for (int pass = 0; pass < 8; ++pass) {
        const int flat = pass * 256 + t;
        const int v = flat >> 5;
        const int c = flat & 31;
        gt[(size_t)(m * NVOX + v0 + v) * FDIM + c] = __float2bfloat16(tile[c][v]);
    }
}

// ---------------------------------------------------------------------------
// Kernel 2: fused sample + PE + MLP
// ---------------------------------------------------------------------------
template <bool TR>
__global__ __launch_bounds__(256, 4) void fused_nerf_kernel(
    const float* __restrict__ points,
    const float* __restrict__ grids,          // original layout (fallback)
    const __hip_bfloat16* __restrict__ gt,    // transposed bf16 (TR path)
    const float* __restrict__ W0, const float* __restrict__ b0,
    const float* __restrict__ W1, const float* __restrict__ b1,
    const float* __restrict__ W2, const float* __restrict__ b2,
    float* __restrict__ density, float* __restrict__ seg) {
    __shared__ float xT[INDIM + 1][XSTR];   // [k][point]
    const int tid = threadIdx.x;
    const int p0  = blockIdx.x * TPB;

    // ---------------- sampling: half-wave per point, lane = channel --------
    {
        const int hw   = tid >> 5;    // 0..7
        const int lane = tid & 31;    // channel
        for (int i = 0; i < TPB / 8; ++i) {
            const int p  = hw * (TPB / 8) + i;
            const int gp = p0 + p;
            const float px = points[gp * 3 + 0];
            const float py = points[gp * 3 + 1];
            const float pz = points[gp * 3 + 2];
            const float ix = (px + 1.0f) * 0.5f * (RESX - 1);
            const float iy = (py + 1.0f) * 0.5f * (RESX - 1);
            const float iz = (pz + 1.0f) * 0.5f * (RESX - 1);
            const float fx0 = floorf(ix), fy0 = floorf(iy), fz0 = floorf(iz);
            const float fx = ix - fx0, fy = iy - fy0, fz = iz - fz0;
            int ix0 = (int)fx0, iy0 = (int)fy0, iz0 = (int)fz0;
            ix0 = min(max(ix0, 0), RESX - 1);
            iy0 = min(max(iy0, 0), RESX - 1);
            iz0 = min(max(iz0, 0), RESX - 1);
            const int ix1 = min(ix0 + 1, RESX - 1);
            const int iy1 = min(iy0 + 1, RESX - 1);
            const int iz1 = min(iz0 + 1, RESX - 1);
            // (weights at clamped duplicate index are exactly 0 for in-range pts)
            const float wx1 = fx, wx0 = 1.0f - fx;
            const float wy1 = fy, wy0 = 1.0f - fy;
            const float wz1 = fz, wz0 = 1.0f - fz;
            const int vz0 = iz0 * 4096, vz1 = iz1 * 4096;
            const int vy0 = iy0 * 64,   vy1 = iy1 * 64;
            const int v000 = vz0 + vy0 + ix0, v001 = vz0 + vy0 + ix1;
            const int v010 = vz0 + vy1 + ix0, v011 = vz0 + vy1 + ix1;
            const int v100 = vz1 + vy0 + ix0, v101 = vz1 + vy0 + ix1;
            const int v110 = vz1 + vy1 + ix0, v111 = vz1 + vy1 + ix1;
            const float w000 = wz0 * wy0 * wx0, w001 = wz0 * wy0 * wx1;
            const float w010 = wz0 * wy1 * wx0, w011 = wz0 * wy1 * wx1;
            const float w100 = wz1 * wy0 * wx0, w101 = wz1 * wy0 * wx1;
            const float w110 = wz1 * wy1 * wx0, w111 = wz1 * wy1 * wx1;
#pragma unroll
            for (int m = 0; m < NMOD; ++m) {
                float acc;
                if (TR) {
                    const __hip_bfloat16* gb = gt + (size_t)m * NVOX * FDIM + lane;
                    acc = w000 * __bfloat162float(gb[(size_t)v000 * FDIM]);
                    acc = fmaf(w001, __bfloat162float(gb[(size_t)v001 * FDIM]), acc);
                    acc = fmaf(w010, __bfloat162float(gb[(size_t)v010 * FDIM]), acc);
                    acc = fmaf(w011, __bfloat162float(gb[(size_t)v011 * FDIM]), acc);
                    acc = fmaf(w100, __bfloat162float(gb[(size_t)v100 * FDIM]), acc);
                    acc = fmaf(w101, __bfloat162float(gb[(size_t)v101 * FDIM]), acc);
                    acc = fmaf(w110, __bfloat162float(gb[(size_t)v110 * FDIM]), acc);
                    acc = fmaf(w111, __bfloat162float(gb[(size_t)v111 * FDIM]), acc);
                } else {
                    const float* gb = grids + (size_t)(m * FDIM + lane) * NVOX;
                    acc = w000 * gb[v000];
                    acc = fmaf(w001, gb[v001], acc);
                    acc = fmaf(w010, gb[v010], acc);
                    acc = fmaf(w011, gb[v011], acc);
                    acc = fmaf(w100, gb[v100], acc);
                    acc = fmaf(w101, gb[v101], acc);
                    acc = fmaf(w110, gb[v110], acc);
                    acc = fmaf(w111, gb[v111], acc);
                }
                xT[m * FDIM + lane][p] = acc;
            }
        }
    }

    // ---------------- positional encoding ---------------------------------
    {
        const int p  = tid & 63;
        const int gq = tid >> 6;    // wave id, uniform per wave
        const int gp = p0 + p;
        float c3[3];
        c3[0] = points[gp * 3 + 0];
        c3[1] = points[gp * 3 + 1];
        c3[2] = points[gp * 3 + 2];
        if (gq == 3) {
#pragma unroll
            for (int d = 0; d < 3; ++d) xT[96 + d][p] = c3[d];
        }
#pragma unroll
        for (int f = 0; f < NFREQ; ++f) {
            if ((f & 3) != gq) continue;   // g0:{0,4} g1:{1,5} g2:{2} g3:{3}
            const float fr = (float)(1 << f);
#pragma unroll
            for (int d = 0; d < 3; ++d) {
                const float a = 3.14159274101257324f * fr * c3[d];
                xT[99 + 6 * f + d][p]     = sinf(a);
                xT[99 + 6 * f + 3 + d][p] = cosf(a);
            }
        }
    }
    __syncthreads();

    // ---------------- MLP: lane = point, wave = 16-output slice ------------
    const int pl = tid & 63;
    const int wv = __builtin_amdgcn_readfirstlane(tid >> 6);   // force SGPR
    const int gp = p0 + pl;

    // layer 0: 135 -> 64
    float acc[16];
#pragma unroll
    for (int j = 0; j < 16; ++j) acc[j] = b0[wv * 16 + j];
    for (int k = 0; k < INDIM; ++k) {
        const float xk = xT[k][pl];
        const float* wr = W0 + k * HID + wv * 16;
#pragma unroll
        for (int j = 0; j < 16; ++j) acc[j] = fmaf(xk, wr[j], acc[j]);
    }
#pragma unroll
    for (int j = 0; j < 16; ++j) acc[j] = fmaxf(acc[j], 0.0f);
    __syncthreads();
#pragma unroll
    for (int j = 0; j < 16; ++j) xT[wv * 16 + j][pl] = acc[j];
    __syncthreads();

    // layer 1: 64 -> 64
    float acc1[16];
#pragma unroll
    for (int j = 0; j < 16; ++j) acc1[j] = b1[wv * 16 + j];
    for (int k = 0; k < HID; ++k) {
        const float xk = xT[k][pl];
        const float* wr = W1 + k * HID + wv * 16;
#pragma unroll
        for (int j = 0; j < 16; ++j) acc1[j] = fmaf(xk, wr[j], acc1[j]);
    }
#pragma unroll
    for (int j = 0; j < 16; ++j) acc1[j] = fmaxf(acc1[j], 0.0f);
    __syncthreads();
#pragma unroll
    for (int j = 0; j < 16; ++j) xT[wv * 16 + j][pl] = acc1[j];
    __syncthreads();

    // layer 2: 64 -> 5, wave 0 only
    if (wv == 0) {
        float o[5];
#pragma unroll
        for (int j = 0; j < 5; ++j) o[j] = b2[j];
        for (int k = 0; k < HID; ++k) {
            const float xk = xT[k][pl];
            const float* wr = W2 + k * (1 + NCLS);
#pragma unroll
            for (int j = 0; j < 5; ++j) o[j] = fmaf(xk, wr[j], o[j]);
        }
        const float d = fmaxf(o[0], 0.0f) + log1pf(expf(-fabsf(o[0])));
        density[gp] = d;
        reinterpret_cast<float4*>(seg)[gp] = make_float4(o[1], o[2], o[3], o[4]);
    }
}

// ---------------------------------------------------------------------------
extern "C" void kernel_launch(void* const* d_in, const int* in_sizes, int n_in,
                              void* d_out, int out_size, void* d_ws, size_t ws_size,
                              hipStream_t stream) {
    const float* points = (const float*)d_in[0];
    const float* grids  = (const float*)d_in[1];
    const float* W0     = (const float*)d_in[2];
    const float* b0     = (const float*)d_in[3];
    const float* W1     = (const float*)d_in[4];
    const float* b1     = (const float*)d_in[5];
    const float* W2     = (const float*)d_in[6];
    const float* b2     = (const float*)d_in[7];

    const int M = in_sizes[0] / 3;               // 524288
    float* density = (float*)d_out;
    float* seg     = density + M;

    const size_t need = (size_t)NMOD * NVOX * FDIM * sizeof(__hip_bfloat16);
    const int nblk = M / TPB;

    if (ws_size >= need) {
        __hip_bfloat16* gt = (__hip_bfloat16*)d_ws;
        transpose_grids_kernel<<<NMOD * (NVOX / 64), 256, 0, stream>>>(grids, gt);
        fused_nerf_kernel<true><<<nblk, 256, 0, stream>>>(
            points, grids, gt, W0, b0, W1, b1, W2, b2, density, seg);
    } else {
        fused_nerf_kernel<false><<<nblk, 256, 0, stream>>>(
            points, grids, (const __hip_bfloat16*)nullptr,
            W0, b0, W1, b1, W2, b2, density, seg);
    }
}

// Round 2
// 198.759 us; speedup vs baseline: 1.4795x; 1.4795x over previous
//
#include <hip/hip_runtime.h>
#include <hip/hip_bf16.h>
#include <math.h>

#define RESX 64
#define NVOX (RESX * RESX * RESX)   // 262144
#define FDIM 32
#define NMOD 3
#define HID 64
#define NCLS 4
#define NFREQ 6
#define INDIM 135                   // 96 + 3 + 36
#define TPB 64                      // points per block
#define XK 168                      // padded K-stride of input X (bf16 elems), 336 B, 16B-aligned
#define HK 72                       // padded stride of hidden acts (144 B, 16B-aligned)
#define XSTR 65                     // old fallback LDS stride

typedef short bf16x8 __attribute__((ext_vector_type(8)));
typedef float f32x4  __attribute__((ext_vector_type(4)));

// ---------------------------------------------------------------------------
// Kernel 1: transpose grids [m][c][64^3] f32  ->  [m][voxel][c] bf16 in d_ws
// ---------------------------------------------------------------------------
__global__ void transpose_grids_kernel(const float* __restrict__ g,
                                       __hip_bfloat16* __restrict__ gt) {
    __shared__ float tile[FDIM][65];
    const int b  = blockIdx.x;          // NMOD * 4096 blocks
    const int m  = b >> 12;
    const int v0 = (b & 4095) << 6;     // 64 voxels per block
    const int t  = threadIdx.x;
#pragma unroll
    for (int pass = 0; pass < 8; ++pass) {
        const int c = pass * 4 + (t >> 6);
        const int v = t & 63;
        tile[c][v] = g[(size_t)(m * FDIM + c) * NVOX + v0 + v];
    }
    __syncthreads();
#pragma unroll
    for (int pass = 0; pass < 8; ++pass) {
        const int flat = pass * 256 + t;
        const int v = flat >> 5;
        const int c = flat & 31;
        gt[(size_t)(m * NVOX + v0 + v) * FDIM + c] = __float2bfloat16(tile[c][v]);
    }
}

// ---------------------------------------------------------------------------
// Kernel 1b: pack W0/W1 into MFMA B-fragment-ready bf16 layout.
// B-frag for mfma_f32_16x16x32_bf16: lane l supplies B[k0 + (l>>4)*8 + j][16*nt + (l&15)]
// layout: wb[(s*4+nt)*64 + l][8] for layer0 (s=0..4), then layer1 (s=0..1) at +10240.
// ---------------------------------------------------------------------------
#define W0PACK (5 * 4 * 64 * 8)     // 10240
#define W1PACK (2 * 4 * 64 * 8)     // 4096
__global__ void pack_weights_kernel(const float* __restrict__ W0,
                                    const float* __restrict__ W1,
                                    __hip_bfloat16* __restrict__ wb) {
    const int t = threadIdx.x;
    for (int idx = t; idx < W0PACK; idx += 256) {
        const int j = idx & 7, l = (idx >> 3) & 63, nt = (idx >> 9) & 3, s = idx >> 11;
        const int k = 32 * s + (l >> 4) * 8 + j;
        const int o = 16 * nt + (l & 15);
        const float v = (k < INDIM) ? W0[k * HID + o] : 0.0f;
        wb[idx] = __float2bfloat16(v);
    }
    for (int idx = t; idx < W1PACK; idx += 256) {
        const int j = idx & 7, l = (idx >> 3) & 63, nt = (idx >> 9) & 3, s = idx >> 11;
        const int k = 32 * s + (l >> 4) * 8 + j;
        const int o = 16 * nt + (l & 15);
        wb[W0PACK + idx] = __float2bfloat16(W1[k * HID + o]);
    }
}

// ---------------------------------------------------------------------------
// Kernel 2: fused sample + PE + MFMA MLP
// ---------------------------------------------------------------------------
__global__ __launch_bounds__(256, 4) void fused_mfma_kernel(
    const float* __restrict__ points,
    const __hip_bfloat16* __restrict__ gt,
    const __hip_bfloat16* __restrict__ wb,
    const float* __restrict__ b0, const float* __restrict__ b1,
    const float* __restrict__ W2, const float* __restrict__ b2,
    float* __restrict__ density, float* __restrict__ seg) {
    __shared__ __align__(16) __hip_bfloat16 Xs[TPB * XK];   // 21504 B; reused as h2
    __shared__ __align__(16) __hip_bfloat16 Hs[TPB * HK];   //  9216 B
    const int tid = threadIdx.x;
    const int p0  = blockIdx.x * TPB;

    // ---------------- sampling: half-wave per point, lane = channel --------
    {
        const int hw   = tid >> 5;    // 0..7
        const int lane = tid & 31;    // channel
        for (int i = 0; i < TPB / 8; ++i) {
            const int p  = hw * (TPB / 8) + i;
            const int gp = p0 + p;
            const float px = points[gp * 3 + 0];
            const float py = points[gp * 3 + 1];
            const float pz = points[gp * 3 + 2];
            const float ix = (px + 1.0f) * 0.5f * (RESX - 1);
            const float iy = (py + 1.0f) * 0.5f * (RESX - 1);
            const float iz = (pz + 1.0f) * 0.5f * (RESX - 1);
            const float fx0 = floorf(ix), fy0 = floorf(iy), fz0 = floorf(iz);
            const float fx = ix - fx0, fy = iy - fy0, fz = iz - fz0;
            int ix0 = (int)fx0, iy0 = (int)fy0, iz0 = (int)fz0;
            ix0 = min(max(ix0, 0), RESX - 1);
            iy0 = min(max(iy0, 0), RESX - 1);
            iz0 = min(max(iz0, 0), RESX - 1);
            const int ix1 = min(ix0 + 1, RESX - 1);
            const int iy1 = min(iy0 + 1, RESX - 1);
            const int iz1 = min(iz0 + 1, RESX - 1);
            const float wx1 = fx, wx0 = 1.0f - fx;
            const float wy1 = fy, wy0 = 1.0f - fy;
            const float wz1 = fz, wz0 = 1.0f - fz;
            const int vz0 = iz0 * 4096, vz1 = iz1 * 4096;
            const int vy0 = iy0 * 64,   vy1 = iy1 * 64;
            const int v000 = vz0 + vy0 + ix0, v001 = vz0 + vy0 + ix1;
            const int v010 = vz0 + vy1 + ix0, v011 = vz0 + vy1 + ix1;
            const int v100 = vz1 + vy0 + ix0, v101 = vz1 + vy0 + ix1;
            const int v110 = vz1 + vy1 + ix0, v111 = vz1 + vy1 + ix1;
            const float w000 = wz0 * wy0 * wx0, w001 = wz0 * wy0 * wx1;
            const float w010 = wz0 * wy1 * wx0, w011 = wz0 * wy1 * wx1;
            const float w100 = wz1 * wy0 * wx0, w101 = wz1 * wy0 * wx1;
            const float w110 = wz1 * wy1 * wx0, w111 = wz1 * wy1 * wx1;
#pragma unroll
            for (int m = 0; m < NMOD; ++m) {
                const __hip_bfloat16* gb = gt + (size_t)m * NVOX * FDIM + lane;
                float acc;
                acc = w000 * __bfloat162float(gb[(size_t)v000 * FDIM]);
                acc = fmaf(w001, __bfloat162float(gb[(size_t)v001 * FDIM]), acc);
                acc = fmaf(w010, __bfloat162float(gb[(size_t)v010 * FDIM]), acc);
                acc = fmaf(w011, __bfloat162float(gb[(size_t)v011 * FDIM]), acc);
                acc = fmaf(w100, __bfloat162float(gb[(size_t)v100 * FDIM]), acc);
                acc = fmaf(w101, __bfloat162float(gb[(size_t)v101 * FDIM]), acc);
                acc = fmaf(w110, __bfloat162float(gb[(size_t)v110 * FDIM]), acc);
                acc = fmaf(w111, __bfloat162float(gb[(size_t)v111 * FDIM]), acc);
                Xs[p * XK + m * FDIM + lane] = __float2bfloat16(acc);
            }
        }
    }

    // ---------------- positional encoding (hw v_sin/v_cos) -----------------
    {
        const int p  = tid & 63;
        const int gq = tid >> 6;    // wave id, uniform per wave
        const int gp = p0 + p;
        float c3[3];
        c3[0] = points[gp * 3 + 0];
        c3[1] = points[gp * 3 + 1];
        c3[2] = points[gp * 3 + 2];
        if (gq == 3) {
#pragma unroll
            for (int d = 0; d < 3; ++d) Xs[p * XK + 96 + d] = __float2bfloat16(c3[d]);
        }
#pragma unroll
        for (int f = 0; f < NFREQ; ++f) {
            if ((f & 3) != gq) continue;   // g0:{0,4} g1:{1,5} g2:{2} g3:{3}
            const float half = 0.5f * (float)(1 << f);   // sin(pi*2^f*x) = sin_hw(fract(x*2^(f-1)))
#pragma unroll
            for (int d = 0; d < 3; ++d) {
                const float r  = c3[d] * half;
                const float rf = r - floorf(r);          // revolutions in [0,1)
                Xs[p * XK + 99 + 6 * f + d]     = __float2bfloat16(__builtin_amdgcn_sinf(rf));
                Xs[p * XK + 99 + 6 * f + 3 + d] = __float2bfloat16(__builtin_amdgcn_cosf(rf));
            }
        }
        // zero-pad K range [135, XK)
        for (int kk = INDIM + gq; kk < XK; kk += 4) Xs[p * XK + kk] = __float2bfloat16(0.0f);
    }
    __syncthreads();

    // ---------------- MFMA MLP --------------------------------------------
    // A-frag (16x32): lane l -> A[l&15][(l>>4)*8 + j];  B-frag: lane l -> B[(l>>4)*8+j][l&15]
    // D: row=(l>>4)*4+r, col=l&15  (m89-verified). K-perm identical for A/B -> robust.
    const int l   = tid & 63;
    const int w   = __builtin_amdgcn_readfirstlane(tid >> 6);   // wave = M-strip (16 pts)
    const int col = l & 15;
    const int g   = l >> 4;

    // ---- layer 0: 135(->160) x 64 ----
    f32x4 acc0[4];
#pragma unroll
    for (int nt = 0; nt < 4; ++nt) {
        const float bv = b0[nt * 16 + col];
        acc0[nt] = (f32x4){bv, bv, bv, bv};
    }
    {
        const __hip_bfloat16* arow = &Xs[(w * 16 + col) * XK];
#pragma unroll
        for (int s = 0; s < 5; ++s) {
            const bf16x8 af = *reinterpret_cast<const bf16x8*>(arow + s * 32 + g * 8);
#pragma unroll
            for (int nt = 0; nt < 4; ++nt) {
                const bf16x8 bfr = *reinterpret_cast<const bf16x8*>(wb + (size_t)((s * 4 + nt) * 64 + l) * 8);
                acc0[nt] = __builtin_amdgcn_mfma_f32_16x16x32_bf16(af, bfr, acc0[nt], 0, 0, 0);
            }
        }
    }
#pragma unroll
    for (int nt = 0; nt < 4; ++nt)
#pragma unroll
        for (int r = 0; r < 4; ++r) {
            const float v = fmaxf(acc0[nt][r], 0.0f);
            Hs[(w * 16 + g * 4 + r) * HK + nt * 16 + col] = __float2bfloat16(v);
        }
    __syncthreads();

    // ---- layer 1: 64 x 64 ----
    f32x4 acc1[4];
#pragma unroll
    for (int nt = 0; nt < 4; ++nt) {
        const float bv = b1[nt * 16 + col];
        acc1[nt] = (f32x4){bv, bv, bv, bv};
    }
    {
        const __hip_bfloat16* arow = &Hs[(w * 16 + col) * HK];
        const __hip_bfloat16* wb1  = wb + W0PACK;
#pragma unroll
        for (int s = 0; s < 2; ++s) {
            const bf16x8 af = *reinterpret_cast<const bf16x8*>(arow + s * 32 + g * 8);
#pragma unroll
            for (int nt = 0; nt < 4; ++nt) {
                const bf16x8 bfr = *reinterpret_cast<const bf16x8*>(wb1 + (size_t)((s * 4 + nt) * 64 + l) * 8);
                acc1[nt] = __builtin_amdgcn_mfma_f32_16x16x32_bf16(af, bfr, acc1[nt], 0, 0, 0);
            }
        }
    }
    __hip_bfloat16* h2 = Xs;   // Xs dead after layer0 (sync above)
#pragma unroll
    for (int nt = 0; nt < 4; ++nt)
#pragma unroll
        for (int r = 0; r < 4; ++r) {
            const float v = fmaxf(acc1[nt][r], 0.0f);
            h2[(w * 16 + g * 4 + r) * HK + nt * 16 + col] = __float2bfloat16(v);
        }
    __syncthreads();

    // ---- layer 2: 64 -> 5 (wave 0, thread per point) ----
    if (tid < 64) {
        const int pt = tid;
        const int gp = p0 + pt;
        float o[5];
#pragma unroll
        for (int j = 0; j < 5; ++j) o[j] = b2[j];
        for (int k = 0; k < HID; ++k) {
            const float xv = __bfloat162float(h2[pt * HK + k]);
            const float* wr = W2 + k * (1 + NCLS);
#pragma unroll
            for (int j = 0; j < 5; ++j) o[j] = fmaf(xv, wr[j], o[j]);
        }
        const float d = fmaxf(o[0], 0.0f) + log1pf(expf(-fabsf(o[0])));
        density[gp] = d;
        reinterpret_cast<float4*>(seg)[gp] = make_float4(o[1], o[2], o[3], o[4]);
    }
}

// ---------------------------------------------------------------------------
// Fallback (no workspace): round-1 f32 VALU path, original grid layout
// ---------------------------------------------------------------------------
__global__ __launch_bounds__(256, 4) void fused_nerf_fallback(
    const float* __restrict__ points,
    const float* __restrict__ grids,
    const float* __restrict__ W0, const float* __restrict__ b0,
    const float* __restrict__ W1, const float* __restrict__ b1,
    const float* __restrict__ W2, const float* __restrict__ b2,
    float* __restrict__ density, float* __restrict__ seg) {
    __shared__ float xT[INDIM + 1][XSTR];
    const int tid = threadIdx.x;
    const int p0  = blockIdx.x * TPB;
    {
        const int hw   = tid >> 5;
        const int lane = tid & 31;
        for (int i = 0; i < TPB / 8; ++i) {
            const int p  = hw * (TPB / 8) + i;
            const int gp = p0 + p;
            const float px = points[gp * 3 + 0];
            const float py = points[gp * 3 + 1];
            const float pz = points[gp * 3 + 2];
            const float ix = (px + 1.0f) * 0.5f * (RESX - 1);
            const float iy = (py + 1.0f) * 0.5f * (RESX - 1);
            const float iz = (pz + 1.0f) * 0.5f * (RESX - 1);
            const float fx0 = floorf(ix), fy0 = floorf(iy), fz0 = floorf(iz);
            const float fx = ix - fx0, fy = iy - fy0, fz = iz - fz0;
            int ix0 = (int)fx0, iy0 = (int)fy0, iz0 = (int)fz0;
            ix0 = min(max(ix0, 0), RESX - 1);
            iy0 = min(max(iy0, 0), RESX - 1);
            iz0 = min(max(iz0, 0), RESX - 1);
            const int ix1 = min(ix0 + 1, RESX - 1);
            const int iy1 = min(iy0 + 1, RESX - 1);
            const int iz1 = min(iz0 + 1, RESX - 1);
            const float wx1 = fx, wx0 = 1.0f - fx;
            const float wy1 = fy, wy0 = 1.0f - fy;
            const float wz1 = fz, wz0 = 1.0f - fz;
            const int vz0 = iz0 * 4096, vz1 = iz1 * 4096;
            const int vy0 = iy0 * 64,   vy1 = iy1 * 64;
            const int v000 = vz0 + vy0 + ix0, v001 = vz0 + vy0 + ix1;
            const int v010 = vz0 + vy1 + ix0, v011 = vz0 + vy1 + ix1;
            const int v100 = vz1 + vy0 + ix0, v101 = vz1 + vy0 + ix1;
            const int v110 = vz1 + vy1 + ix0, v111 = vz1 + vy1 + ix1;
            const float w000 = wz0 * wy0 * wx0, w001 = wz0 * wy0 * wx1;
            const float w010 = wz0 * wy1 * wx0, w011 = wz0 * wy1 * wx1;
            const float w100 = wz1 * wy0 * wx0, w101 = wz1 * wy0 * wx1;
            const float w110 = wz1 * wy1 * wx0, w111 = wz1 * wy1 * wx1;
#pragma unroll
            for (int m = 0; m < NMOD; ++m) {
                const float* gb = grids + (size_t)(m * FDIM + lane) * NVOX;
                float acc;
                acc = w000 * gb[v000];
                acc = fmaf(w001, gb[v001], acc);
                acc = fmaf(w010, gb[v010], acc);
                acc = fmaf(w011, gb[v011], acc);
                acc = fmaf(w100, gb[v100], acc);
                acc = fmaf(w101, gb[v101], acc);
                acc = fmaf(w110, gb[v110], acc);
                acc = fmaf(w111, gb[v111], acc);
                xT[m * FDIM + lane][p] = acc;
            }
        }
    }
    {
        const int p  = tid & 63;
        const int gq = tid >> 6;
        const int gp = p0 + p;
        float c3[3];
        c3[0] = points[gp * 3 + 0];
        c3[1] = points[gp * 3 + 1];
        c3[2] = points[gp * 3 + 2];
        if (gq == 3) {
#pragma unroll
            for (int d = 0; d < 3; ++d) xT[96 + d][p] = c3[d];
        }
#pragma unroll
        for (int f = 0; f < NFREQ; ++f) {
            if ((f & 3) != gq) continue;
            const float fr = (float)(1 << f);
#pragma unroll
            for (int d = 0; d < 3; ++d) {
                const float a = 3.14159274101257324f * fr * c3[d];
                xT[99 + 6 * f + d][p]     = sinf(a);
                xT[99 + 6 * f + 3 + d][p] = cosf(a);
            }
        }
    }
    __syncthreads();
    const int pl = tid & 63;
    const int wv = __builtin_amdgcn_readfirstlane(tid >> 6);
    const int gp = p0 + pl;
    float acc[16];
#pragma unroll
    for (int j = 0; j < 16; ++j) acc[j] = b0[wv * 16 + j];
    for (int k = 0; k < INDIM; ++k) {
        const float xk = xT[k][pl];
        const float* wr = W0 + k * HID + wv * 16;
#pragma unroll
        for (int j = 0; j < 16; ++j) acc[j] = fmaf(xk, wr[j], acc[j]);
    }
#pragma unroll
    for (int j = 0; j < 16; ++j) acc[j] = fmaxf(acc[j], 0.0f);
    __syncthreads();
#pragma unroll
    for (int j = 0; j < 16; ++j) xT[wv * 16 + j][pl] = acc[j];
    __syncthreads();
    float acc1[16];
#pragma unroll
    for (int j = 0; j < 16; ++j) acc1[j] = b1[wv * 16 + j];
    for (int k = 0; k < HID; ++k) {
        const float xk = xT[k][pl];
        const float* wr = W1 + k * HID + wv * 16;
#pragma unroll
        for (int j = 0; j < 16; ++j) acc1[j] = fmaf(xk, wr[j], acc1[j]);
    }
#pragma unroll
    for (int j = 0; j < 16; ++j) acc1[j] = fmaxf(acc1[j], 0.0f);
    __syncthreads();
#pragma unroll
    for (int j = 0; j < 16; ++j) xT[wv * 16 + j][pl] = acc1[j];
    __syncthreads();
    if (wv == 0) {
        float o[5];
#pragma unroll
        for (int j = 0; j < 5; ++j) o[j] = b2[j];
        for (int k = 0; k < HID; ++k) {
            const float xk = xT[k][pl];
            const float* wr = W2 + k * (1 + NCLS);
#pragma unroll
            for (int j = 0; j < 5; ++j) o[j] = fmaf(xk, wr[j], o[j]);
        }
        const float d = fmaxf(o[0], 0.0f) + log1pf(expf(-fabsf(o[0])));
        density[gp] = d;
        reinterpret_cast<float4*>(seg)[gp] = make_float4(o[1], o[2], o[3], o[4]);
    }
}

// ---------------------------------------------------------------------------
extern "C" void kernel_launch(void* const* d_in, const int* in_sizes, int n_in,
                              void* d_out, int out_size, void* d_ws, size_t ws_size,
                              hipStream_t stream) {
    const float* points = (const float*)d_in[0];
    const float* grids  = (const float*)d_in[1];
    const float* W0     = (const float*)d_in[2];
    const float* b0     = (const float*)d_in[3];
    const float* W1     = (const float*)d_in[4];
    const float* b1     = (const float*)d_in[5];
    const float* W2     = (const float*)d_in[6];
    const float* b2     = (const float*)d_in[7];

    const int M = in_sizes[0] / 3;               // 524288
    float* density = (float*)d_out;
    float* seg     = density + M;

    const size_t need   = (size_t)NMOD * NVOX * FDIM * sizeof(__hip_bfloat16);  // 48 MiB
    const size_t wbytes = (size_t)(W0PACK + W1PACK) * sizeof(__hip_bfloat16);   // 28672 B
    const int nblk = M / TPB;

    if (ws_size >= need + wbytes) {
        __hip_bfloat16* gt = (__hip_bfloat16*)d_ws;
        __hip_bfloat16* wb = (__hip_bfloat16*)((char*)d_ws + need);
        transpose_grids_kernel<<<NMOD * (NVOX / 64), 256, 0, stream>>>(grids, gt);
        pack_weights_kernel<<<1, 256, 0, stream>>>(W0, W1, wb);
        fused_mfma_kernel<<<nblk, 256, 0, stream>>>(
            points, gt, wb, b0, b1, W2, b2, density, seg);
    } else {
        fused_nerf_fallback<<<nblk, 256, 0, stream>>>(
            points, grids, W0, b0, W1, b1, W2, b2, density, seg);
    }
}

// Round 3
// 189.944 us; speedup vs baseline: 1.5482x; 1.0464x over previous
//
#include <hip/hip_runtime.h>
#include <hip/hip_bf16.h>
#include <math.h>

#define RESX 64
#define NVOX (RESX * RESX * RESX)   // 262144
#define FDIM 32
#define NMOD 3
#define HID 64
#define NCLS 4
#define NFREQ 6
#define INDIM 135                   // 96 + 3 + 36
#define TPB 64                      // points per block
#define XK 168                      // padded K-stride of input X (bf16), 336 B
#define HK 72                       // padded stride of hidden acts (144 B)
#define XSTR 65                     // fallback LDS stride
#define MSTRIDE_U (NVOX * FDIM / 2) // module stride in uints (4,194,304)

typedef short bf16x8 __attribute__((ext_vector_type(8)));
typedef float f32x4  __attribute__((ext_vector_type(4)));

static __device__ __forceinline__ float ubf_lo(unsigned int u) {
    return __uint_as_float(u << 16);
}
static __device__ __forceinline__ float ubf_hi(unsigned int u) {
    return __uint_as_float(u & 0xFFFF0000u);
}
static __device__ __forceinline__ unsigned int pack_bf16(float lo, float hi) {
    __hip_bfloat16 a = __float2bfloat16(lo);
    __hip_bfloat16 b = __float2bfloat16(hi);
    unsigned short ua = *reinterpret_cast<unsigned short*>(&a);
    unsigned short ub = *reinterpret_cast<unsigned short*>(&b);
    return ((unsigned int)ub << 16) | ua;
}

// ---------------------------------------------------------------------------
// Kernel 1: transpose grids [m][c][64^3] f32  ->  [m][voxel][c] bf16 in d_ws
// ---------------------------------------------------------------------------
__global__ void transpose_grids_kernel(const float* __restrict__ g,
                                       __hip_bfloat16* __restrict__ gt) {
    __shared__ float tile[FDIM][65];
    const int b  = blockIdx.x;          // NMOD * 4096 blocks
    const int m  = b >> 12;
    const int v0 = (b & 4095) << 6;     // 64 voxels per block
    const int t  = threadIdx.x;
#pragma unroll
    for (int pass = 0; pass < 8; ++pass) {
        const int c = pass * 4 + (t >> 6);
        const int v = t & 63;
        tile[c][v] = g[(size_t)(m * FDIM + c) * NVOX + v0 + v];
    }
    __syncthreads();
    unsigned int* gtu = reinterpret_cast<unsigned int*>(gt);
#pragma unroll
    for (int pass = 0; pass < 4; ++pass) {
        const int flat = pass * 256 + t;    // 0..1023 = 64 vox * 16 uints
        const int v  = flat >> 4;
        const int cu = flat & 15;
        gtu[(size_t)(m * NVOX + v0 + v) * 16 + cu] =
            pack_bf16(tile[2 * cu][v], tile[2 * cu + 1][v]);
    }
}

// ---------------------------------------------------------------------------
// Kernel 1b: pack W0/W1/W2 into MFMA B-fragment-ready bf16 layout.
// B-frag for mfma_f32_16x16x32_bf16: lane l supplies B[32s + (l>>4)*8 + j][16*nt + (l&15)]
// ---------------------------------------------------------------------------
#define W0PACK (5 * 4 * 64 * 8)     // 10240
#define W1PACK (2 * 4 * 64 * 8)     // 4096
#define W2PACK (2 * 64 * 8)         // 1024
__global__ void pack_weights_kernel(const float* __restrict__ W0,
                                    const float* __restrict__ W1,
                                    const float* __restrict__ W2,
                                    __hip_bfloat16* __restrict__ wb) {
    const int t  = blockIdx.x * 256 + threadIdx.x;
    const int NT = gridDim.x * 256;
    for (int idx = t; idx < W0PACK; idx += NT) {
        const int j = idx & 7, l = (idx >> 3) & 63, nt = (idx >> 9) & 3, s = idx >> 11;
        const int k = 32 * s + (l >> 4) * 8 + j;
        const int o = 16 * nt + (l & 15);
        const float v = (k < INDIM) ? W0[k * HID + o] : 0.0f;
        wb[idx] = __float2bfloat16(v);
    }
    for (int idx = t; idx < W1PACK; idx += NT) {
        const int j = idx & 7, l = (idx >> 3) & 63, nt = (idx >> 9) & 3, s = idx >> 11;
        const int k = 32 * s + (l >> 4) * 8 + j;
        const int o = 16 * nt + (l & 15);
        wb[W0PACK + idx] = __float2bfloat16(W1[k * HID + o]);
    }
    for (int idx = t; idx < W2PACK; idx += NT) {
        const int j = idx & 7, l = (idx >> 3) & 63, s = idx >> 9;
        const int k = 32 * s + (l >> 4) * 8 + j;
        const int o = l & 15;
        wb[W0PACK + W1PACK + idx] =
            __float2bfloat16((o < NCLS + 1) ? W2[k * (NCLS + 1) + o] : 0.0f);
    }
}

// ---------------------------------------------------------------------------
// Kernel 2: fused sample + PE + full-MFMA MLP
// ---------------------------------------------------------------------------
__global__ __launch_bounds__(256, 5) void fused_mfma_kernel(
    const float* __restrict__ points,
    const __hip_bfloat16* __restrict__ gt,
    const __hip_bfloat16* __restrict__ wb,
    const float* __restrict__ b0, const float* __restrict__ b1,
    const float* __restrict__ b2,
    float* __restrict__ density, float* __restrict__ seg) {
    __shared__ __align__(16) __hip_bfloat16 Xs[TPB * XK];   // 21504 B; reused as h2
    __shared__ __align__(16) __hip_bfloat16 Hs[TPB * HK];   //  9216 B; reused as Os
    const int tid = threadIdx.x;
    const int p0  = blockIdx.x * TPB;

    // -------- sampling: half-wave per point, pair-corner 128B gathers ------
    {
        const int hw   = tid >> 5;    // 0..7  (half-wave id)
        const int lane = tid & 31;
        const int half = lane >> 4;   // 0 => x0 corner, 1 => x1 corner
        const int lc   = lane & 15;   // channel-pair index
        const unsigned int* gtu = reinterpret_cast<const unsigned int*>(gt) + lane;
        for (int i = 0; i < TPB / 8; ++i) {
            const int p  = hw * (TPB / 8) + i;
            const int gp = p0 + p;
            const float px = points[gp * 3 + 0];
            const float py = points[gp * 3 + 1];
            const float pz = points[gp * 3 + 2];
            const float ix = (px + 1.0f) * 0.5f * (RESX - 1);
            const float iy = (py + 1.0f) * 0.5f * (RESX - 1);
            const float iz = (pz + 1.0f) * 0.5f * (RESX - 1);
            const float fx0 = floorf(ix), fy0 = floorf(iy), fz0 = floorf(iz);
            const float fx = ix - fx0, fy = iy - fy0, fz = iz - fz0;
            int x0 = (int)fx0, y0 = (int)fy0, z0 = (int)fz0;
            x0 = min(max(x0, 0), RESX - 1);
            y0 = min(max(y0, 0), RESX - 1);
            z0 = min(max(z0, 0), RESX - 1);
            const int y1 = min(y0 + 1, RESX - 1);
            const int z1 = min(z0 + 1, RESX - 1);
            // (points are uniform in [-1,1): x0<=62, so [x0,x0+1] never leaves the row)
            const float wxh = half ? fx : 1.0f - fx;   // this lane's x-half weight
            const float wy0 = 1.0f - fy, wy1 = fy;
            const float wz0 = 1.0f - fz, wz1 = fz;
            const int b00 = (z0 * 4096 + y0 * 64 + x0) * 16;
            const int b01 = (z0 * 4096 + y1 * 64 + x0) * 16;
            const int b10 = (z1 * 4096 + y0 * 64 + x0) * 16;
            const int b11 = (z1 * 4096 + y1 * 64 + x0) * 16;
            const float w00 = wz0 * wy0 * wxh, w01 = wz0 * wy1 * wxh;
            const float w10 = wz1 * wy0 * wxh, w11 = wz1 * wy1 * wxh;
            float alo[NMOD], ahi[NMOD];
#pragma unroll
            for (int m = 0; m < NMOD; ++m) {
                const unsigned int* gm = gtu + m * MSTRIDE_U;
                const unsigned int u0 = gm[b00];
                const unsigned int u1 = gm[b01];
                const unsigned int u2 = gm[b10];
                const unsigned int u3 = gm[b11];
                float lo, hi;
                lo = w00 * ubf_lo(u0);              hi = w00 * ubf_hi(u0);
                lo = fmaf(w01, ubf_lo(u1), lo);     hi = fmaf(w01, ubf_hi(u1), hi);
                lo = fmaf(w10, ubf_lo(u2), lo);     hi = fmaf(w10, ubf_hi(u2), hi);
                lo = fmaf(w11, ubf_lo(u3), lo);     hi = fmaf(w11, ubf_hi(u3), hi);
                alo[m] = lo; ahi[m] = hi;
            }
#pragma unroll
            for (int m = 0; m < NMOD; ++m) {
                const float lo = alo[m] + __shfl_xor(alo[m], 16, 64);
                const float hi = ahi[m] + __shfl_xor(ahi[m], 16, 64);
                if (lane < 16) {
                    *reinterpret_cast<unsigned int*>(&Xs[p * XK + m * FDIM + 2 * lc]) =
                        pack_bf16(lo, hi);
                }
            }
        }
    }

    // ---------------- positional encoding (hw v_sin/v_cos) -----------------
    {
        const int p  = tid & 63;
        const int gq = tid >> 6;    // wave id, uniform per wave
        const int gp = p0 + p;
        float c3[3];
        c3[0] = points[gp * 3 + 0];
        c3[1] = points[gp * 3 + 1];
        c3[2] = points[gp * 3 + 2];
        if (gq == 3) {
#pragma unroll
            for (int d = 0; d < 3; ++d) Xs[p * XK + 96 + d] = __float2bfloat16(c3[d]);
        }
#pragma unroll
        for (int f = 0; f < NFREQ; ++f) {
            if ((f & 3) != gq) continue;   // g0:{0,4} g1:{1,5} g2:{2} g3:{3}
            const float half = 0.5f * (float)(1 << f);   // sin(pi*2^f*x)=sin_hw(fract(x*2^(f-1)))
#pragma unroll
            for (int d = 0; d < 3; ++d) {
                const float r  = c3[d] * half;
                const float rf = r - floorf(r);          // revolutions in [0,1)
                Xs[p * XK + 99 + 6 * f + d]     = __float2bfloat16(__builtin_amdgcn_sinf(rf));
                Xs[p * XK + 99 + 6 * f + 3 + d] = __float2bfloat16(__builtin_amdgcn_cosf(rf));
            }
        }
        // zero-pad K range [135, XK)
        for (int kk = INDIM + gq; kk < XK; kk += 4) Xs[p * XK + kk] = __float2bfloat16(0.0f);
    }
    __syncthreads();

    // ---------------- MFMA MLP --------------------------------------------
    // A-frag: lane l -> A[l&15][(l>>4)*8+j]; B-frag: lane l -> B[(l>>4)*8+j][l&15]
    // D: row=(l>>4)*4+r, col=l&15  (m89-verified).
    const int l   = tid & 63;
    const int w   = __builtin_amdgcn_readfirstlane(tid >> 6);   // wave = 16-point strip
    const int col = l & 15;
    const int g   = l >> 4;

    // ---- layer 0: 135(->160) x 64 ----
    f32x4 acc0[4];
#pragma unroll
    for (int nt = 0; nt < 4; ++nt) {
        const float bv = b0[nt * 16 + col];
        acc0[nt] = (f32x4){bv, bv, bv, bv};
    }
    {
        const __hip_bfloat16* arow = &Xs[(w * 16 + col) * XK];
#pragma unroll
        for (int s = 0; s < 5; ++s) {
            const bf16x8 af = *reinterpret_cast<const bf16x8*>(arow + s * 32 + g * 8);
#pragma unroll
            for (int nt = 0; nt < 4; ++nt) {
                const bf16x8 bfr = *reinterpret_cast<const bf16x8*>(wb + (size_t)((s * 4 + nt) * 64 + l) * 8);
                acc0[nt] = __builtin_amdgcn_mfma_f32_16x16x32_bf16(af, bfr, acc0[nt], 0, 0, 0);
            }
        }
    }
#pragma unroll
    for (int nt = 0; nt < 4; ++nt)
#pragma unroll
        for (int r = 0; r < 4; ++r) {
            const float v = fmaxf(acc0[nt][r], 0.0f);
            Hs[(w * 16 + g * 4 + r) * HK + nt * 16 + col] = __float2bfloat16(v);
        }
    __syncthreads();

    // ---- layer 1: 64 x 64 ----
    f32x4 acc1[4];
#pragma unroll
    for (int nt = 0; nt < 4; ++nt) {
        const float bv = b1[nt * 16 + col];
        acc1[nt] = (f32x4){bv, bv, bv, bv};
    }
    {
        const __hip_bfloat16* arow = &Hs[(w * 16 + col) * HK];
        const __hip_bfloat16* wb1  = wb + W0PACK;
#pragma unroll
        for (int s = 0; s < 2; ++s) {
            const bf16x8 af = *reinterpret_cast<const bf16x8*>(arow + s * 32 + g * 8);
#pragma unroll
            for (int nt = 0; nt < 4; ++nt) {
                const bf16x8 bfr = *reinterpret_cast<const bf16x8*>(wb1 + (size_t)((s * 4 + nt) * 64 + l) * 8);
                acc1[nt] = __builtin_amdgcn_mfma_f32_16x16x32_bf16(af, bfr, acc1[nt], 0, 0, 0);
            }
        }
    }
    __hip_bfloat16* h2 = Xs;   // Xs dead after layer0 reads (sync above)
#pragma unroll
    for (int nt = 0; nt < 4; ++nt)
#pragma unroll
        for (int r = 0; r < 4; ++r) {
            const float v = fmaxf(acc1[nt][r], 0.0f);
            h2[(w * 16 + g * 4 + r) * HK + nt * 16 + col] = __float2bfloat16(v);
        }
    __syncthreads();

    // ---- layer 2: 64 -> 5 (padded 16) via MFMA ----
    f32x4 acc2;
    {
        const float bv = (col < NCLS + 1) ? b2[col] : 0.0f;
        acc2 = (f32x4){bv, bv, bv, bv};
        const __hip_bfloat16* arow = &h2[(w * 16 + col) * HK];
        const __hip_bfloat16* wb2  = wb + W0PACK + W1PACK;
#pragma unroll
        for (int s = 0; s < 2; ++s) {
            const bf16x8 af  = *reinterpret_cast<const bf16x8*>(arow + s * 32 + g * 8);
            const bf16x8 bfr = *reinterpret_cast<const bf16x8*>(wb2 + (size_t)(s * 64 + l) * 8);
            acc2 = __builtin_amdgcn_mfma_f32_16x16x32_bf16(af, bfr, acc2, 0, 0, 0);
        }
    }
    float* Os = reinterpret_cast<float*>(Hs);   // Hs dead after layer1 reads
    if (col < 8) {
#pragma unroll
        for (int r = 0; r < 4; ++r) Os[(w * 16 + g * 4 + r) * 8 + col] = acc2[r];
    }
    __syncthreads();

    // ---- epilogue: softplus + stores, one thread per point ----
    if (tid < TPB) {
        const int pt  = tid;
        const int gp2 = p0 + pt;
        const float o0 = Os[pt * 8 + 0];
        const float e  = __builtin_amdgcn_exp2f(fabsf(o0) * -1.44269504f);   // exp(-|o0|)
        const float sp = fmaxf(o0, 0.0f) + 0.69314718f * __builtin_amdgcn_logf(1.0f + e);
        density[gp2] = sp;
        reinterpret_cast<float4*>(seg)[gp2] =
            make_float4(Os[pt * 8 + 1], Os[pt * 8 + 2], Os[pt * 8 + 3], Os[pt * 8 + 4]);
    }
}

// ---------------------------------------------------------------------------
// Fallback (no workspace): f32 VALU path, original grid layout
// ---------------------------------------------------------------------------
__global__ __launch_bounds__(256, 4) void fused_nerf_fallback(
    const float* __restrict__ points,
    const float* __restrict__ grids,
    const float* __restrict__ W0, const float* __restrict__ b0,
    const float* __restrict__ W1, const float* __restrict__ b1,
    const float* __restrict__ W2, const float* __restrict__ b2,
    float* __restrict__ density, float* __restrict__ seg) {
    __shared__ float xT[INDIM + 1][XSTR];
    const int tid = threadIdx.x;
    const int p0  = blockIdx.x * TPB;
    {
        const int hw   = tid >> 5;
        const int lane = tid & 31;
        for (int i = 0; i < TPB / 8; ++i) {
            const int p  = hw * (TPB / 8) + i;
            const int gp = p0 + p;
            const float px = points[gp * 3 + 0];
            const float py = points[gp * 3 + 1];
            const float pz = points[gp * 3 + 2];
            const float ix = (px + 1.0f) * 0.5f * (RESX - 1);
            const float iy = (py + 1.0f) * 0.5f * (RESX - 1);
            const float iz = (pz + 1.0f) * 0.5f * (RESX - 1);
            const float fx0 = floorf(ix), fy0 = floorf(iy), fz0 = floorf(iz);
            const float fx = ix - fx0, fy = iy - fy0, fz = iz - fz0;
            int ix0 = (int)fx0, iy0 = (int)fy0, iz0 = (int)fz0;
            ix0 = min(max(ix0, 0), RESX - 1);
            iy0 = min(max(iy0, 0), RESX - 1);
            iz0 = min(max(iz0, 0), RESX - 1);
            const int ix1 = min(ix0 + 1, RESX - 1);
            const int iy1 = min(iy0 + 1, RESX - 1);
            const int iz1 = min(iz0 + 1, RESX - 1);
            const float wx1 = fx, wx0 = 1.0f - fx;
            const float wy1 = fy, wy0 = 1.0f - fy;
            const float wz1 = fz, wz0 = 1.0f - fz;
            const int vz0 = iz0 * 4096, vz1 = iz1 * 4096;
            const int vy0 = iy0 * 64,   vy1 = iy1 * 64;
            const int v000 = vz0 + vy0 + ix0, v001 = vz0 + vy0 + ix1;
            const int v010 = vz0 + vy1 + ix0, v011 = vz0 + vy1 + ix1;
            const int v100 = vz1 + vy0 + ix0, v101 = vz1 + vy0 + ix1;
            const int v110 = vz1 + vy1 + ix0, v111 = vz1 + vy1 + ix1;
            const float w000 = wz0 * wy0 * wx0, w001 = wz0 * wy0 * wx1;
            const float w010 = wz0 * wy1 * wx0, w011 = wz0 * wy1 * wx1;
            const float w100 = wz1 * wy0 * wx0, w101 = wz1 * wy0 * wx1;
            const float w110 = wz1 * wy1 * wx0, w111 = wz1 * wy1 * wx1;
#pragma unroll
            for (int m = 0; m < NMOD; ++m) {
                const float* gb = grids + (size_t)(m * FDIM + lane) * NVOX;
                float acc;
                acc = w000 * gb[v000];
                acc = fmaf(w001, gb[v001], acc);
                acc = fmaf(w010, gb[v010], acc);
                acc = fmaf(w011, gb[v011], acc);
                acc = fmaf(w100, gb[v100], acc);
                acc = fmaf(w101, gb[v101], acc);
                acc = fmaf(w110, gb[v110], acc);
                acc = fmaf(w111, gb[v111], acc);
                xT[m * FDIM + lane][p] = acc;
            }
        }
    }
    {
        const int p  = tid & 63;
        const int gq = tid >> 6;
        const int gp = p0 + p;
        float c3[3];
        c3[0] = points[gp * 3 + 0];
        c3[1] = points[gp * 3 + 1];
        c3[2] = points[gp * 3 + 2];
        if (gq == 3) {
#pragma unroll
            for (int d = 0; d < 3; ++d) xT[96 + d][p] = c3[d];
        }
#pragma unroll
        for (int f = 0; f < NFREQ; ++f) {
            if ((f & 3) != gq) continue;
            const float fr = (float)(1 << f);
#pragma unroll
            for (int d = 0; d < 3; ++d) {
                const float a = 3.14159274101257324f * fr * c3[d];
                xT[99 + 6 * f + d][p]     = sinf(a);
                xT[99 + 6 * f + 3 + d][p] = cosf(a);
            }
        }
    }
    __syncthreads();
    const int pl = tid & 63;
    const int wv = __builtin_amdgcn_readfirstlane(tid >> 6);
    const int gp = p0 + pl;
    float acc[16];
#pragma unroll
    for (int j = 0; j < 16; ++j) acc[j] = b0[wv * 16 + j];
    for (int k = 0; k < INDIM; ++k) {
        const float xk = xT[k][pl];
        const float* wr = W0 + k * HID + wv * 16;
#pragma unroll
        for (int j = 0; j < 16; ++j) acc[j] = fmaf(xk, wr[j], acc[j]);
    }
#pragma unroll
    for (int j = 0; j < 16; ++j) acc[j] = fmaxf(acc[j], 0.0f);
    __syncthreads();
#pragma unroll
    for (int j = 0; j < 16; ++j) xT[wv * 16 + j][pl] = acc[j];
    __syncthreads();
    float acc1[16];
#pragma unroll
    for (int j = 0; j < 16; ++j) acc1[j] = b1[wv * 16 + j];
    for (int k = 0; k < HID; ++k) {
        const float xk = xT[k][pl];
        const float* wr = W1 + k * HID + wv * 16;
#pragma unroll
        for (int j = 0; j < 16; ++j) acc1[j] = fmaf(xk, wr[j], acc1[j]);
    }
#pragma unroll
    for (int j = 0; j < 16; ++j) acc1[j] = fmaxf(acc1[j], 0.0f);
    __syncthreads();
#pragma unroll
    for (int j = 0; j < 16; ++j) xT[wv * 16 + j][pl] = acc1[j];
    __syncthreads();
    if (wv == 0) {
        float o[5];
#pragma unroll
        for (int j = 0; j < 5; ++j) o[j] = b2[j];
        for (int k = 0; k < HID; ++k) {
            const float xk = xT[k][pl];
            const float* wr = W2 + k * (1 + NCLS);
#pragma unroll
            for (int j = 0; j < 5; ++j) o[j] = fmaf(xk, wr[j], o[j]);
        }
        const float d = fmaxf(o[0], 0.0f) + log1pf(expf(-fabsf(o[0])));
        density[gp] = d;
        reinterpret_cast<float4*>(seg)[gp] = make_float4(o[1], o[2], o[3], o[4]);
    }
}

// ---------------------------------------------------------------------------
extern "C" void kernel_launch(void* const* d_in, const int* in_sizes, int n_in,
                              void* d_out, int out_size, void* d_ws, size_t ws_size,
                              hipStream_t stream) {
    const float* points = (const float*)d_in[0];
    const float* grids  = (const float*)d_in[1];
    const float* W0     = (const float*)d_in[2];
    const float* b0     = (const float*)d_in[3];
    const float* W1     = (const float*)d_in[4];
    const float* b1     = (const float*)d_in[5];
    const float* W2     = (const float*)d_in[6];
    const float* b2     = (const float*)d_in[7];

    const int M = in_sizes[0] / 3;               // 524288
    float* density = (float*)d_out;
    float* seg     = density + M;

    const size_t need   = (size_t)NMOD * NVOX * FDIM * sizeof(__hip_bfloat16);        // 48 MiB
    const size_t wbytes = (size_t)(W0PACK + W1PACK + W2PACK) * sizeof(__hip_bfloat16);
    const int nblk = M / TPB;

    if (ws_size >= need + wbytes) {
        __hip_bfloat16* gt = (__hip_bfloat16*)d_ws;
        __hip_bfloat16* wb = (__hip_bfloat16*)((char*)d_ws + need);
        transpose_grids_kernel<<<NMOD * (NVOX / 64), 256, 0, stream>>>(grids, gt);
        pack_weights_kernel<<<15, 256, 0, stream>>>(W0, W1, W2, wb);
        fused_mfma_kernel<<<nblk, 256, 0, stream>>>(
            points, gt, wb, b0, b1, b2, density, seg);
    } else {
        fused_nerf_fallback<<<nblk, 256, 0, stream>>>(
            points, grids, W0, b0, W1, b1, W2, b2, density, seg);
    }
}